// Round 12
// baseline (824.215 us; speedup 1.0000x reference)
//
#include <hip/hip_runtime.h>
#include <math.h>

namespace {

constexpr int nB = 16, nR = 400, nT = 400, nH = 8, nQ = 64;
constexpr int BH = nB * nH;   // 128
constexpr int HQ = nH * nQ;   // 512
constexpr int KP = 416;       // padded K for bf16 GEMMs (13 x 32)
constexpr int NK = KP / 32;   // 13 K-chunks

typedef __attribute__((ext_vector_type(8))) short short8;
typedef __attribute__((ext_vector_type(4))) float floatx4;

__device__ __forceinline__ unsigned short f2bf(float f) {
  unsigned int u = __float_as_uint(f);
  unsigned int r = (u + 0x7fffu + ((u >> 16) & 1u)) >> 16;
  return (unsigned short)r;
}
__device__ __forceinline__ float bf2f(unsigned short u) {
  return __uint_as_float(((unsigned int)u) << 16);
}

// async global->LDS DMA, 16B per lane; LDS dest is wave-uniform base + lane*16
__device__ __forceinline__ void dma16(const void* g, void* l) {
  __builtin_amdgcn_global_load_lds(
      (const __attribute__((address_space(1))) unsigned int*)g,
      (__attribute__((address_space(3))) unsigned int*)l, 16, 0, 0);
}

// ---------------- generic fp32 GEMM: C = act(A@W + bias) ----------------
template<int BM, int BN, int BK, int TM, int TN, bool RELU>
__global__ __launch_bounds__(256) void gemm_k(
    const float* __restrict__ A, const float* __restrict__ W,
    const float* __restrict__ bias,
    float* C, int M, int N, int K)
{
  constexpr int NT = (BM / TM) * (BN / TN);
  static_assert(NT == 256, "block must be 256 threads");
  __shared__ float As[BK][BM + 4];
  __shared__ float Bs[BK][BN + 4];
  const int tid = threadIdx.x;
  const int bm = blockIdx.y * BM;
  const int bn = blockIdx.x * BN;
  const int tx = tid % (BN / TN);
  const int ty = tid / (BN / TN);
  const bool n4ok = ((N & 3) == 0);

  float acc[TM][TN];
#pragma unroll
  for (int i = 0; i < TM; ++i)
#pragma unroll
    for (int j = 0; j < TN; ++j) acc[i][j] = 0.f;

  for (int kt = 0; kt < K; kt += BK) {
#pragma unroll
    for (int i = 0; i < (BM * BK) / (NT * 4); ++i) {
      int flat = (tid + i * NT) * 4;
      int m = flat / BK;
      int k = flat % BK;
      float4 v = *(const float4*)(A + (size_t)(bm + m) * K + kt + k);
      As[k + 0][m] = v.x; As[k + 1][m] = v.y;
      As[k + 2][m] = v.z; As[k + 3][m] = v.w;
    }
#pragma unroll
    for (int i = 0; i < (BK * BN) / (NT * 4); ++i) {
      int flat = (tid + i * NT) * 4;
      int k = flat / BN;
      int n = flat % BN;
      int gn = bn + n;
      float4 v;
      if (n4ok && gn + 3 < N) {
        v = *(const float4*)(W + (size_t)(kt + k) * N + gn);
      } else {
        v.x = (gn + 0 < N) ? W[(size_t)(kt + k) * N + gn + 0] : 0.f;
        v.y = (gn + 1 < N) ? W[(size_t)(kt + k) * N + gn + 1] : 0.f;
        v.z = (gn + 2 < N) ? W[(size_t)(kt + k) * N + gn + 2] : 0.f;
        v.w = (gn + 3 < N) ? W[(size_t)(kt + k) * N + gn + 3] : 0.f;
      }
      *(float4*)&Bs[k][n] = v;
    }
    __syncthreads();
#pragma unroll
    for (int k = 0; k < BK; ++k) {
      float a[TM], b[TN];
#pragma unroll
      for (int i = 0; i < TM; i += 4)
        *(float4*)&a[i] = *(const float4*)&As[k][ty * TM + i];
#pragma unroll
      for (int j = 0; j < TN; j += 4)
        *(float4*)&b[j] = *(const float4*)&Bs[k][tx * TN + j];
#pragma unroll
      for (int i = 0; i < TM; ++i)
#pragma unroll
        for (int j = 0; j < TN; ++j) acc[i][j] += a[i] * b[j];
    }
    __syncthreads();
  }

#pragma unroll
  for (int i = 0; i < TM; ++i) {
    const int gm = bm + ty * TM + i;
    float* crow = C + (size_t)gm * N;
#pragma unroll
    for (int j = 0; j < TN; j += 4) {
      const int gn = bn + tx * TN + j;
      if (n4ok && gn + 3 < N) {
        float4 bv = *(const float4*)(bias + gn);
        float4 v;
        v.x = acc[i][j + 0] + bv.x; v.y = acc[i][j + 1] + bv.y;
        v.z = acc[i][j + 2] + bv.z; v.w = acc[i][j + 3] + bv.w;
        if (RELU) {
          v.x = fmaxf(v.x, 0.f); v.y = fmaxf(v.y, 0.f);
          v.z = fmaxf(v.z, 0.f); v.w = fmaxf(v.w, 0.f);
        }
        *(float4*)(crow + gn) = v;
      } else {
#pragma unroll
        for (int jj = 0; jj < 4; ++jj) {
          int gnn = gn + jj;
          if (gnn < N) {
            float v = acc[i][j + jj] + bias[gnn];
            if (RELU) v = fmaxf(v, 0.f);
            crow[gnn] = v;
          }
        }
      }
    }
  }
}

// ---------------- split-bf16 prep: rows [6400][400] fp32 -> hi/lo bf16 [6400][416]
__global__ void xsplit_k(const float* __restrict__ x,
                         unsigned short* __restrict__ xh,
                         unsigned short* __restrict__ xl)
{
  int i = blockIdx.x * 256 + threadIdx.x;      // 4-col group id
  constexpr int total = 6400 * (KP / 4);       // 665,600
  if (i >= total) return;
  int row = i / (KP / 4), cg = i - row * (KP / 4);
  int c = cg * 4;
  ushort4 h = make_ushort4(0, 0, 0, 0), l = make_ushort4(0, 0, 0, 0);
  if (c < 400) {
    float4 v = *(const float4*)(x + (size_t)row * 400 + c);
    h.x = f2bf(v.x); l.x = f2bf(v.x - bf2f(h.x));
    h.y = f2bf(v.y); l.y = f2bf(v.y - bf2f(h.y));
    h.z = f2bf(v.z); l.z = f2bf(v.z - bf2f(h.z));
    h.w = f2bf(v.w); l.w = f2bf(v.w - bf2f(h.w));
  }
  *(ushort4*)(xh + (size_t)row * KP + c) = h;
  *(ushort4*)(xl + (size_t)row * KP + c) = l;
}

// ---------------- fused head-fusion + split: feats(bf16,8 heads) -> xh/xl ------
__global__ void hfx_k(const unsigned short* __restrict__ feats,
                      const float* __restrict__ fw, const float* __restrict__ fb,
                      unsigned short* __restrict__ xh,
                      unsigned short* __restrict__ xl)
{
  int i = blockIdx.x * 256 + threadIdx.x;      // 4-col group id
  constexpr int total = 6400 * (KP / 4);       // 665,600
  if (i >= total) return;
  int row = i / (KP / 4), cg = i - row * (KP / 4);
  int c = cg * 4;
  ushort4 h = make_ushort4(0, 0, 0, 0), l = make_ushort4(0, 0, 0, 0);
  if (c < 400) {
    const int bb = row / nR;
    const int r = row - bb * nR;
    float fbv = fb[0];
    float4 acc = {fbv, fbv, fbv, fbv};
#pragma unroll
    for (int hh = 0; hh < nH; ++hh) {
      float w = fw[hh];
      ushort4 v = *(const ushort4*)(feats +
          (((size_t)(bb * nH + hh) * nR + r) * nT + c));
      acc.x += w * bf2f(v.x); acc.y += w * bf2f(v.y);
      acc.z += w * bf2f(v.z); acc.w += w * bf2f(v.w);
    }
    h.x = f2bf(acc.x); l.x = f2bf(acc.x - bf2f(h.x));
    h.y = f2bf(acc.y); l.y = f2bf(acc.y - bf2f(h.y));
    h.z = f2bf(acc.z); l.z = f2bf(acc.z - bf2f(h.z));
    h.w = f2bf(acc.w); l.w = f2bf(acc.w - bf2f(h.w));
  }
  *(ushort4*)(xh + (size_t)row * KP + c) = h;
  *(ushort4*)(xl + (size_t)row * KP + c) = l;
}

// ---------------- W prep: [K][N] fp32 -> n-major hi/lo bf16 [N][KPo] -----------
// grid (KPo/32, N/32); zero-pads rows k in [K, KPo).
__global__ void wksplit_k(const float* __restrict__ W, int K, int N, int KPo,
                          unsigned short* __restrict__ Wth,
                          unsigned short* __restrict__ Wtl)
{
  __shared__ float t[32][33];
  const int k0 = blockIdx.x * 32;
  const int n0 = blockIdx.y * 32;
  const int tx = threadIdx.x, ty = threadIdx.y;   // 32 x 8
#pragma unroll
  for (int r = 0; r < 32; r += 8) {
    int k = k0 + ty + r, n = n0 + tx;
    t[ty + r][tx] = (k < K) ? W[(size_t)k * N + n] : 0.f;
  }
  __syncthreads();
#pragma unroll
  for (int r = 0; r < 32; r += 8) {
    int n = n0 + ty + r, k = k0 + tx;
    float v = t[tx][ty + r];
    unsigned short h = f2bf(v);
    Wth[(size_t)n * KPo + k] = h;
    Wtl[(size_t)n * KPo + k] = f2bf(v - bf2f(h));
  }
}

// ---------------- split-bf16 MFMA GEMM: C = act(A@W + bias), fp32-class accuracy
// C ~= Ah@Bh + Ah@Bl + Al@Bh (dropped Al@Bl ~ 2^-18 relative).
// NKt = K/32 (A/B stride = NKt*32). OSPLIT: epilogue writes hi/lo bf16 pairs
// (stride N) feeding the next split-bf16 layer; else fp32 C.
// Counted-vmcnt ledger is NKt-invariant: prologue stages chunks 0,1;
// vmcnt(4) steady / vmcnt(0) at k==NKt-1; buffer (k+2)%3 was last read at
// k-1 and all waves passed barrier k -> safe to overwrite.
template<int NKt, bool RELU, bool OSPLIT>
__global__ __launch_bounds__(256) void sgemm_mfma(
    const unsigned short* __restrict__ Ah, const unsigned short* __restrict__ Al,
    const unsigned short* __restrict__ Bh, const unsigned short* __restrict__ Bl,
    const float* __restrict__ bias,
    float* __restrict__ C, unsigned short* __restrict__ Ch,
    unsigned short* __restrict__ Cl, int N)
{
  constexpr int KA = NKt * 32;
  // 3 x 16KB stage buffers; epilogue Os (64x68 fp32 = 17.4KB) aliases
  __shared__ __align__(16) char smem[49152];

  const int tid = threadIdx.x;
  const int lane = tid & 63;
  const int wave = tid >> 6;

  const int bm = blockIdx.y * 64;
  const int bn = blockIdx.x * 64;

  const int wm = (wave & 1) * 32;
  const int wn = (wave >> 1) * 32;

  // wave w stages kind w entirely: 0 Ah, 1 Al, 2 Bh, 3 Bl (4 x 1KB groups)
  const unsigned short* kbase = (wave == 0) ? Ah : (wave == 1) ? Al
                              : (wave == 2) ? Bh : Bl;
  const int rbase0 = (wave < 2) ? bm : bn;
  const unsigned short* gsrc[4];
  int goff[4];
#pragma unroll
  for (int j = 0; j < 4; ++j) {
    const int row = rbase0 + j * 16 + (lane & 15);
    gsrc[j] = kbase + (size_t)row * KA + (lane >> 4) * 8;
    goff[j] = (wave * 4 + j) * 1024;
  }

  // prologue: chunk 0 -> buf0, chunk 1 -> buf1
#pragma unroll
  for (int j = 0; j < 4; ++j) dma16(gsrc[j], smem + goff[j]);
#pragma unroll
  for (int j = 0; j < 4; ++j) dma16(gsrc[j] + 32, smem + 16384 + goff[j]);

  floatx4 acc[2][2] = {};
  const int ao = (wm >> 4) * 1024;            // {0, 2048}
  const int bo = (wn >> 4) * 1024;
  const int lb = lane * 16;

#pragma unroll
  for (int k = 0; k < NKt; ++k) {
    if (k == NKt - 1)
      asm volatile("s_waitcnt vmcnt(0)" ::: "memory");
    else
      asm volatile("s_waitcnt vmcnt(4)" ::: "memory");
    __builtin_amdgcn_s_barrier();
    __builtin_amdgcn_sched_barrier(0);
    if (k + 2 < NKt) {
      char* dst = smem + ((k + 2) % 3) * 16384;
#pragma unroll
      for (int j = 0; j < 4; ++j)
        dma16(gsrc[j] + (k + 2) * 32, dst + goff[j]);
    }
    const char* base = smem + (k % 3) * 16384;
    short8 ah[2], al[2], bh[2], bl[2];
#pragma unroll
    for (int mi = 0; mi < 2; ++mi) {
      ah[mi] = *(const short8*)(base + ao + mi * 1024 + lb);
      al[mi] = *(const short8*)(base + 4096 + ao + mi * 1024 + lb);
    }
#pragma unroll
    for (int ni = 0; ni < 2; ++ni) {
      bh[ni] = *(const short8*)(base + 8192 + bo + ni * 1024 + lb);
      bl[ni] = *(const short8*)(base + 12288 + bo + ni * 1024 + lb);
    }
#pragma unroll
    for (int mi = 0; mi < 2; ++mi)
#pragma unroll
      for (int ni = 0; ni < 2; ++ni) {
        acc[mi][ni] = __builtin_amdgcn_mfma_f32_16x16x32_bf16(
            ah[mi], bh[ni], acc[mi][ni], 0, 0, 0);
        acc[mi][ni] = __builtin_amdgcn_mfma_f32_16x16x32_bf16(
            ah[mi], bl[ni], acc[mi][ni], 0, 0, 0);
        acc[mi][ni] = __builtin_amdgcn_mfma_f32_16x16x32_bf16(
            al[mi], bh[ni], acc[mi][ni], 0, 0, 0);
      }
  }

  float* Os = (float*)smem;   // aliases staging buffers
  __syncthreads();            // all waves' last ds_reads done before overwrite
#pragma unroll
  for (int mi = 0; mi < 2; ++mi)
#pragma unroll
    for (int ni = 0; ni < 2; ++ni)
#pragma unroll
      for (int r = 0; r < 4; ++r) {
        const int lrow = wm + mi * 16 + (lane >> 4) * 4 + r;
        const int cl = wn + ni * 16 + (lane & 15);
        Os[lrow * 68 + cl] = acc[mi][ni][r];
      }
  __syncthreads();

#pragma unroll
  for (int ii = 0; ii < 4; ++ii) {
    const int f = tid + ii * 256;     // 1024 slots = 64 rows x 16 float4 groups
    const int row = f >> 4;
    const int c4 = (f & 15) << 2;
    float4 v = *(const float4*)&Os[row * 68 + c4];
    float4 bb = *(const float4*)(bias + bn + c4);
    v.x += bb.x; v.y += bb.y; v.z += bb.z; v.w += bb.w;
    if (RELU) {
      v.x = fmaxf(v.x, 0.f); v.y = fmaxf(v.y, 0.f);
      v.z = fmaxf(v.z, 0.f); v.w = fmaxf(v.w, 0.f);
    }
    if (OSPLIT) {
      ushort4 h, l;
      h.x = f2bf(v.x); l.x = f2bf(v.x - bf2f(h.x));
      h.y = f2bf(v.y); l.y = f2bf(v.y - bf2f(h.y));
      h.z = f2bf(v.z); l.z = f2bf(v.z - bf2f(h.z));
      h.w = f2bf(v.w); l.w = f2bf(v.w - bf2f(h.w));
      *(ushort4*)(Ch + (size_t)(bm + row) * N + bn + c4) = h;
      *(ushort4*)(Cl + (size_t)(bm + row) * N + bn + c4) = l;
    } else {
      *(float4*)(C + (size_t)(bm + row) * N + bn + c4) = v;
    }
  }
}

// ---------------- bf16 MFMA GEMM for GCN layers — counted-vmcnt pipeline ------
// R23 form (R17 K-loop frozen + single-pass epilogue). Do not retile.
__global__ __launch_bounds__(256) void gcn_gemm(
    const unsigned short* __restrict__ A,    // msg [51200][416] bf16
    const unsigned short* __restrict__ Bt,   // Wt [416][416] bf16 n-major
    const float* __restrict__ bias,
    unsigned short* __restrict__ Cb,         // feats [51200][400] bf16
    const float* __restrict__ x, int first)
{
  // 3 stage buffers x (A 8KB | B 4KB) = 36864 B; epilogue Os (34816 B) aliases
  __shared__ __align__(16) char smem[36864];

  const int tid = threadIdx.x;
  const int lane = tid & 63;
  const int wave = tid >> 6;

  // XCD-local decode: 350 blocks per XCD; n-tiles of one m-tile consecutive.
  const int b = blockIdx.x;
  const int xcd = b & 7;
  const int s = b >> 3;          // 0..349
  const int loc = s / 7;         // 0..49
  const int nt = s - loc * 7;    // 0..6
  const int mt = loc * 8 + xcd;  // 0..399
  const int bm = mt * 128;
  const int bn = nt * 64;

  const int wm = (wave & 1) * 64;
  const int wn = (wave >> 1) * 32;

  // --- DMA setup: 12 x 1KB groups per K-chunk (8 A + 4 B), 3 per wave.
  const unsigned short* gsrc[3];
  int goff[3];                       // byte offset within one 12KB buffer
#pragma unroll
  for (int j = 0; j < 3; ++j) {
    const int g = wave * 3 + j;
    if (g < 8) {
      const int row = bm + g * 16 + (lane & 15);
      gsrc[j] = A + (size_t)row * KP + (lane >> 4) * 8;
      goff[j] = g * 1024;
    } else {
      int row = bn + (g - 8) * 16 + (lane & 15);
      if (row > 415) row = 415;
      gsrc[j] = Bt + (size_t)row * KP + (lane >> 4) * 8;
      goff[j] = 8192 + (g - 8) * 1024;
    }
  }

  // Residual preload (T14): oldest vmem ops; drained by iter-0's vmcnt wait.
  const int rcol = bn + ((tid & 15) << 2);
  ushort4 resv[2][4];
  if (!first && rcol < nT) {
#pragma unroll
    for (int rh = 0; rh < 2; ++rh)
#pragma unroll
      for (int ii = 0; ii < 4; ++ii) {
        const int gr = bm + rh * 64 + (tid >> 4) + ii * 16;
        resv[rh][ii] = *(const ushort4*)(Cb + (size_t)gr * nT + rcol);
      }
  }

  // prologue: stage chunk 0 -> buf0, chunk 1 -> buf1
#pragma unroll
  for (int j = 0; j < 3; ++j)
    dma16(gsrc[j], smem + goff[j]);
#pragma unroll
  for (int j = 0; j < 3; ++j)
    dma16(gsrc[j] + 32, smem + 12288 + goff[j]);

  floatx4 acc[4][2] = {};
  const int aoff = (wm >> 4) * 1024;          // {0, 4096}
  const int boff = 8192 + (wn >> 4) * 1024;   // {8192, 10240}
  const int lb = lane * 16;

#pragma unroll
  for (int k = 0; k < NK; ++k) {
    // wait this wave's chunk-k stages; count = # newer in-flight stage ops
    if (k == NK - 1)
      asm volatile("s_waitcnt vmcnt(0)" ::: "memory");
    else
      asm volatile("s_waitcnt vmcnt(3)" ::: "memory");
    __builtin_amdgcn_s_barrier();            // all waves' chunk-k resident
    __builtin_amdgcn_sched_barrier(0);       // no ds_read migration upward
    if (k + 2 < NK) {                        // stage chunk k+2 (buffer read at k-1)
      char* dst = smem + ((k + 2) % 3) * 12288;
#pragma unroll
      for (int j = 0; j < 3; ++j)
        dma16(gsrc[j] + (k + 2) * 32, dst + goff[j]);
    }
    const char* base = smem + (k % 3) * 12288;
    short8 av[4], bv[2];
#pragma unroll
    for (int mi = 0; mi < 4; ++mi)
      av[mi] = *(const short8*)(base + aoff + mi * 1024 + lb);
#pragma unroll
    for (int ni = 0; ni < 2; ++ni)
      bv[ni] = *(const short8*)(base + boff + ni * 1024 + lb);
#pragma unroll
    for (int mi = 0; mi < 4; ++mi)
#pragma unroll
      for (int ni = 0; ni < 2; ++ni)
        acc[mi][ni] = __builtin_amdgcn_mfma_f32_16x16x32_bf16(
            av[mi], bv[ni], acc[mi][ni], 0, 0, 0);
  }

  // bias per ni (C/D layout: col = lane&15, row = (lane>>4)*4 + reg)
  float bvv[2];
#pragma unroll
  for (int ni = 0; ni < 2; ++ni) {
    const int col = bn + wn + ni * 16 + (lane & 15);
    bvv[ni] = (col < nT) ? bias[col] : 0.f;
  }

  float* Os = (float*)smem;   // 128 x 68 fp32 = 34816 B, aliases staging bufs

  // single-pass epilogue: all 4 waves write relu(acc+bias) for their own
  // 64-row slab (disjoint wm) -> one barrier pair, one 2048-item store pass.
  __syncthreads();            // all waves done reading chunk-12's buffer
#pragma unroll
  for (int mi = 0; mi < 4; ++mi)
#pragma unroll
    for (int ni = 0; ni < 2; ++ni)
#pragma unroll
      for (int r = 0; r < 4; ++r) {
        const int lrow = wm + mi * 16 + (lane >> 4) * 4 + r;
        const int cl = wn + ni * 16 + (lane & 15);
        Os[lrow * 68 + cl] = fmaxf(acc[mi][ni][r] + bvv[ni], 0.f);
      }
  __syncthreads();

#pragma unroll
  for (int ii = 0; ii < 8; ++ii) {
    const int f = tid + ii * 256;     // 2048 slots = 128 rows x 16 col-groups
    const int row = f >> 4;           // = ii*16 + (tid>>4)
    const int c4 = (f & 15) << 2;
    const int col = bn + c4;
    if (col < nT) {
      const int gr = bm + row;
      float4 v = *(const float4*)&Os[row * 68 + c4];
      float r0, r1, r2, r3;
      if (first) {
        const int bh = gr / nR;
        const int rr = gr - bh * nR;
        const float* rrow = x + (size_t)(bh >> 3) * (nR * nT) + (size_t)rr * nT;
        float4 rv = *(const float4*)(rrow + col);
        r0 = rv.x; r1 = rv.y; r2 = rv.z; r3 = rv.w;
      } else {
        ushort4 rv = resv[ii >> 2][ii & 3];   // same gr/rcol mapping as load
        r0 = bf2f(rv.x); r1 = bf2f(rv.y); r2 = bf2f(rv.z); r3 = bf2f(rv.w);
      }
      ushort4 o;
      o.x = f2bf(v.x + r0); o.y = f2bf(v.y + r1);
      o.z = f2bf(v.z + r2); o.w = f2bf(v.w + r3);
      *(ushort4*)(Cb + (size_t)gr * nT + col) = o;
    }
  }
}

// ---------------- W prep: Wt[i][n][k] = bf16(gcn_W[i][k][n]), zero-padded ------
__global__ void wprep_k(const float* __restrict__ W, unsigned short* __restrict__ Wt)
{
  __shared__ float t[32][33];
  const int i = blockIdx.z;
  const int k0 = blockIdx.x * 32;
  const int n0 = blockIdx.y * 32;
  const int tx = threadIdx.x, ty = threadIdx.y;   // 32 x 8
#pragma unroll
  for (int r = 0; r < 32; r += 8) {
    int k = k0 + ty + r, n = n0 + tx;
    t[ty + r][tx] = (k < nT && n < nT) ? W[(size_t)i * nT * nT + (size_t)k * nT + n] : 0.f;
  }
  __syncthreads();
#pragma unroll
  for (int r = 0; r < 32; r += 8) {
    int n = n0 + ty + r, k = k0 + tx;
    Wt[(size_t)i * KP * KP + (size_t)n * KP + k] = f2bf(t[tx][ty + r]);
  }
}

// ---------------- SE gate (gap == 1/R identically) -----------------------------
__global__ void gate_k(const float* __restrict__ w1, const float* __restrict__ b1,
                       const float* __restrict__ w2, const float* __restrict__ b2,
                       float* gate)
{
  if (threadIdx.x == 0 && blockIdx.x == 0) {
    float h1[4];
    const float gap = 1.0f / 400.0f;
#pragma unroll
    for (int i = 0; i < 4; ++i) {
      float s = b1[i];
      for (int h = 0; h < 8; ++h) s += gap * w1[h * 4 + i];
      h1[i] = fmaxf(s, 0.f);
    }
#pragma unroll
    for (int h = 0; h < 8; ++h) {
      float s = b2[h];
      for (int i = 0; i < 4; ++i) s += h1[i] * w2[i * 8 + h];
      gate[h] = 1.f / (1.f + expf(-s));
    }
  }
}

// ---------------- batched QK^T scores: sc = relu((Q@K^T)/8), symmetric ---------
__global__ __launch_bounds__(256) void qkscore_k(
    const float* __restrict__ qk, float* __restrict__ sc)
{
  __shared__ float Qs[64][68];   // Qs[k][m]
  __shared__ float Ks[64][68];   // Ks[k][n]

  const int tm = blockIdx.y;
  const int tn = blockIdx.x;
  if (tm > tn) return;           // symmetry: skip lower triangle

  const int tid = threadIdx.x;
  const int bh = blockIdx.z;
  const int b = bh >> 3, h = bh & 7;
  const int bm = tm * 64;
  const int bn = tn * 64;
  const float* qkb = qk + (size_t)b * nR * HQ + h * nQ;

  {
    const int row = tid & 63;                 // = lane -> conflict-free LDS writes
#pragma unroll
    for (int p = 0; p < 4; ++p) {
      const int kc = (tid >> 6) + p * 4;
      int gr = bm + row; if (gr > 399) gr = 399;
      float4 v = *(const float4*)(qkb + (size_t)gr * HQ + (kc << 2));
      Qs[kc * 4 + 0][row] = v.x; Qs[kc * 4 + 1][row] = v.y;
      Qs[kc * 4 + 2][row] = v.z; Qs[kc * 4 + 3][row] = v.w;
      int gs2 = bn + row; if (gs2 > 399) gs2 = 399;
      float4 w = *(const float4*)(qkb + (size_t)gs2 * HQ + (kc << 2));
      Ks[kc * 4 + 0][row] = w.x; Ks[kc * 4 + 1][row] = w.y;
      Ks[kc * 4 + 2][row] = w.z; Ks[kc * 4 + 3][row] = w.w;
    }
  }
  __syncthreads();

  const int tx = tid & 15;
  const int ty = tid >> 4;
  float acc[4][4] = {};
#pragma unroll 8
  for (int k = 0; k < 64; ++k) {
    float4 a = *(const float4*)&Qs[k][ty * 4];
    float4 bv = *(const float4*)&Ks[k][tx * 4];
    acc[0][0] += a.x * bv.x; acc[0][1] += a.x * bv.y; acc[0][2] += a.x * bv.z; acc[0][3] += a.x * bv.w;
    acc[1][0] += a.y * bv.x; acc[1][1] += a.y * bv.y; acc[1][2] += a.y * bv.z; acc[1][3] += a.y * bv.w;
    acc[2][0] += a.z * bv.x; acc[2][1] += a.z * bv.y; acc[2][2] += a.z * bv.z; acc[2][3] += a.z * bv.w;
    acc[3][0] += a.w * bv.x; acc[3][1] += a.w * bv.y; acc[3][2] += a.w * bv.z; acc[3][3] += a.w * bv.w;
  }

  float* scb = sc + (size_t)bh * nR * 400;

  {
    const int gc = bn + tx * 4;
    if (gc < 400) {
#pragma unroll
      for (int i = 0; i < 4; ++i) {
        const int gr = bm + ty * 4 + i;
        if (gr < 400) {
          float4 o;
          o.x = fmaxf(acc[i][0] * 0.125f, 0.f);
          o.y = fmaxf(acc[i][1] * 0.125f, 0.f);
          o.z = fmaxf(acc[i][2] * 0.125f, 0.f);
          o.w = fmaxf(acc[i][3] * 0.125f, 0.f);
          *(float4*)(scb + (size_t)gr * 400 + gc) = o;
        }
      }
    }
  }

  if (tm != tn) {
    const int gc = bm + ty * 4;
    if (gc < 400) {
#pragma unroll
      for (int j = 0; j < 4; ++j) {
        const int gr = bn + tx * 4 + j;
        if (gr < 400) {
          float4 o;
          o.x = fmaxf(acc[0][j] * 0.125f, 0.f);
          o.y = fmaxf(acc[1][j] * 0.125f, 0.f);
          o.z = fmaxf(acc[2][j] * 0.125f, 0.f);
          o.w = fmaxf(acc[3][j] * 0.125f, 0.f);
          *(float4*)(scb + (size_t)gr * 400 + gc) = o;
        }
      }
    }
  }
}

// ---------------- softmax + gate + stable-rank mask -> sparse adj --------------
__global__ __launch_bounds__(256) void rankadj_k(
    const float* __restrict__ sc, const float* __restrict__ gate,
    float* __restrict__ adjval, int* __restrict__ adjcol)
{
  __shared__ float rowbuf[4][408];

  const int wave = threadIdx.x >> 6;
  const int lane = threadIdx.x & 63;
  const int row = blockIdx.x * 4 + wave;
  const int bh = row / nR;
  const int r = row - bh * nR;
  const float* srow = sc + (size_t)row * 400;

  float v[7];
  bool valid[7];
#pragma unroll
  for (int it = 0; it < 7; ++it) {
    const int j = lane + it * 64;
    valid[it] = (j < 400);
    v[it] = valid[it] ? srow[j] : 0.f;
  }

  float m = 0.f;
#pragma unroll
  for (int it = 0; it < 7; ++it) m = fmaxf(m, v[it]);
#pragma unroll
  for (int o = 32; o > 0; o >>= 1) m = fmaxf(m, __shfl_xor(m, o));

  float e[7];
  float s = 0.f;
#pragma unroll
  for (int it = 0; it < 7; ++it) {
    e[it] = valid[it] ? expf(v[it] - m) : 0.f;
    s += e[it];
  }
#pragma unroll
  for (int o = 32; o > 0; o >>= 1) s += __shfl_xor(s, o);

  const float g = gate[bh & 7];
  float val[7];
#pragma unroll
  for (int it = 0; it < 7; ++it) val[it] = (e[it] / s) * g;

#pragma unroll
  for (int it = 0; it < 7; ++it)
    if (valid[it]) rowbuf[wave][lane + it * 64] = val[it];
  __syncthreads();

  const int csp[6] = {0, 16, 17, 18, 19, 20};
  float vc[6];
#pragma unroll
  for (int i = 0; i < 6; ++i) vc[i] = rowbuf[wave][csp[i]];
  int rk[6] = {0, 0, 0, 0, 0, 0};
#pragma unroll
  for (int it = 0; it < 7; ++it) {
    if (valid[it]) {
      const int j = lane + it * 64;
      const float vj = val[it];
#pragma unroll
      for (int i = 0; i < 6; ++i)
        rk[i] += (vj < vc[i]) ? 1 : ((vj == vc[i] && j < csp[i]) ? 1 : 0);
    }
  }
#pragma unroll
  for (int i = 0; i < 6; ++i)
#pragma unroll
    for (int o = 32; o > 0; o >>= 1) rk[i] += __shfl_xor(rk[i], o);

  if (lane == 0) {
    const size_t base = (size_t)row * 8;
    bool dup = false;
#pragma unroll
    for (int i = 0; i < 6; ++i) {
      const int p = rk[i];
      adjcol[base + i] = p;
      adjval[base + i] = rowbuf[wave][p];
      dup = dup || (p == r);
    }
    adjcol[base + 6] = r;
    adjval[base + 6] = dup ? 0.f : rowbuf[wave][r];
    adjcol[base + 7] = r;
    adjval[base + 7] = 0.f;
  }
}

// ---------------- sparse msg via LDS-staged feats(bf16), 32-col chunks ---------
// R24: R20 structure (proven); gather now 32B/item (800 items) — halves
// adjacency loads, addressing and loop iterations per output byte. LDS layout
// (stride 36 shorts = 72B, 16 bank positions for random rows) unchanged.
__global__ __launch_bounds__(256) void spmsg_k(
    const int* __restrict__ adjcol, const float* __restrict__ adjval,
    const unsigned short* __restrict__ feats, const float* __restrict__ x,
    int first, unsigned short* __restrict__ msg)
{
  __shared__ unsigned short fs[400 * 36];   // 28.8 KB

  const int tid = threadIdx.x;
  const int bh = blockIdx.x;
  const int c0 = blockIdx.y * 32;           // 13 chunks cover 416 (>=400 pad)

  // stage: 400 rows x 32 cols bf16, 16B per item (r, g: 8-col group)
  if (first) {
    const float* src = x + (size_t)(bh >> 3) * (nR * nT);
    for (int i = tid; i < 1600; i += 256) {
      const int r = i >> 2, g = i & 3;
      const int c = c0 + g * 8;
      ushort4 lo = make_ushort4(0, 0, 0, 0), hi = make_ushort4(0, 0, 0, 0);
      if (c < 400) {
        float4 v0 = *(const float4*)(src + (size_t)r * nT + c);
        float4 v1 = *(const float4*)(src + (size_t)r * nT + c + 4);
        lo = make_ushort4(f2bf(v0.x), f2bf(v0.y), f2bf(v0.z), f2bf(v0.w));
        hi = make_ushort4(f2bf(v1.x), f2bf(v1.y), f2bf(v1.z), f2bf(v1.w));
      }
      *(ushort4*)&fs[r * 36 + g * 8] = lo;
      *(ushort4*)&fs[r * 36 + g * 8 + 4] = hi;
    }
  } else {
    const unsigned short* src = feats + (size_t)bh * nR * nT;
    for (int i = tid; i < 1600; i += 256) {
      const int r = i >> 2, g = i & 3;
      const int c = c0 + g * 8;
      short8 v = {};
      if (c < 400) v = *(const short8*)(src + (size_t)r * nT + c);
      *(short8*)&fs[r * 36 + g * 8] = v;
    }
  }
  __syncthreads();

  const int* ac = adjcol + (size_t)bh * nR * 8;
  const float* av = adjval + (size_t)bh * nR * 8;
  for (int i = tid; i < 800; i += 256) {       // 32B per item
    const int r = i >> 1, g2 = i & 1;          // 16-col half
    const int c = c0 + g2 * 16;
    unsigned short* o = msg + ((size_t)bh * nR + r) * KP + c;
    if (c >= 400) {               // pad cols 400-415: must be zero for GEMM
      short8 z = {};
      *(short8*)o = z;
      *(short8*)(o + 8) = z;
      continue;
    }
    int4 c03 = *(const int4*)(ac + r * 8);
    int4 c47 = *(const int4*)(ac + r * 8 + 4);
    float4 v03 = *(const float4*)(av + r * 8);
    float4 v47 = *(const float4*)(av + r * 8 + 4);
    const int col[7] = {c03.x, c03.y, c03.z, c03.w, c47.x, c47.y, c47.z};
    const float val[7] = {v03.x, v03.y, v03.z, v03.w, v47.x, v47.y, v47.z};
    float a[16] = {};
#pragma unroll
    for (int j = 0; j < 7; ++j) {
      const int fb = col[j] * 36 + g2 * 16;
      short8 v0 = *(const short8*)&fs[fb];
      short8 v1 = *(const short8*)&fs[fb + 8];
      const float w = val[j];
#pragma unroll
      for (int e = 0; e < 8; ++e) {
        a[e] += w * bf2f((unsigned short)v0[e]);
        a[e + 8] += w * bf2f((unsigned short)v1[e]);
      }
    }
    short8 ov0, ov1;
#pragma unroll
    for (int e = 0; e < 8; ++e) {
      ov0[e] = (short)f2bf(a[e]);
      ov1[e] = (short)f2bf(a[e + 8]);
    }
    *(short8*)o = ov0;
    *(short8*)(o + 8) = ov1;
  }
}

}  // namespace

extern "C" void kernel_launch(void* const* d_in, const int* in_sizes, int n_in,
                              void* d_out, int out_size, void* d_ws, size_t ws_size,
                              hipStream_t stream)
{
  (void)in_sizes; (void)n_in; (void)out_size; (void)ws_size;
  const float* x    = (const float*)d_in[0];
  const float* Wk   = (const float*)d_in[1];
  const float* bk   = (const float*)d_in[2];
  const float* seW1 = (const float*)d_in[3];
  const float* seb1 = (const float*)d_in[4];
  const float* seW2 = (const float*)d_in[5];
  const float* seb2 = (const float*)d_in[6];
  const float* gcnW = (const float*)d_in[7];
  const float* gcnb = (const float*)d_in[8];
  const float* fw   = (const float*)d_in[9];
  const float* fb   = (const float*)d_in[10];
  const float* mW1  = (const float*)d_in[11];
  const float* mb1  = (const float*)d_in[12];
  const float* mW2  = (const float*)d_in[13];
  const float* mb2  = (const float*)d_in[14];
  const float* mW3  = (const float*)d_in[15];
  const float* mb3  = (const float*)d_in[16];
  const float* mW4  = (const float*)d_in[17];
  const float* mb4  = (const float*)d_in[18];
  float* out = (float*)d_out;

  // workspace (float units), total ~103 MB:
  // [adjval][adjcol][gate][Wt][qk][region: scores fp32 (82MB) ∪
  //   {featsb bf16 41MB ; msg bf16 42.6MB}]
  float* ws     = (float*)d_ws;
  float* adjval = ws;                                         //   409,600 f
  int*   adjcol = (int*)(adjval + 409600);                    //   409,600 i
  float* gate   = (float*)(adjcol + 409600);                  //        64 f
  unsigned short* Wt = (unsigned short*)(gate + 64);          //   692,224 f
  float* qk     = gate + 64 + 692224;                         // 3,276,800 f
  float* region = qk + (size_t)3276800;
  float* scores = region;                                     // 20,480,000 f
  unsigned short* featsb = (unsigned short*)region;           // 10,240,000 f-eq
  unsigned short* msg = (unsigned short*)(region + 10240000); // 10,649,600 f-eq

  // qk-path split-bf16 operand aliases (scores region, dead before scores write)
  unsigned short* xh  = (unsigned short*)region;              // 6400*416
  unsigned short* xl  = xh + (size_t)6400 * KP;
  unsigned short* Wth = xl + (size_t)6400 * KP;               // 512*416
  unsigned short* Wtl = Wth + (size_t)512 * KP;

  // MLP-path aliases in the MSG region (dead after last gcn_gemm); ~23MB < 42.6MB
  unsigned short* mxh  = (unsigned short*)msg;                // 6400*416
  unsigned short* mxl  = mxh + (size_t)6400 * KP;
  unsigned short* mWth = mxl + (size_t)6400 * KP;             // 256*416
  unsigned short* mWtl = mWth + (size_t)256 * KP;
  unsigned short* h1h  = mWtl + (size_t)256 * KP;             // 6400*256
  unsigned short* h1l  = h1h + (size_t)6400 * 256;
  unsigned short* w2h  = h1l + (size_t)6400 * 256;            // 128*256
  unsigned short* w2l  = w2h + (size_t)128 * 256;
  unsigned short* h2h  = w2l + (size_t)128 * 256;             // 6400*128
  unsigned short* h2l  = h2h + (size_t)6400 * 128;
  unsigned short* w3h  = h2l + (size_t)6400 * 128;            // 64*128
  unsigned short* w3l  = w3h + (size_t)64 * 128;
  float* h3 = (float*)(w3l + (size_t)64 * 128 + 64);          // 6400*64 f (aligned)

  // 0. gcn_W -> bf16, transposed (n-major), zero-padded to 416x416
  wprep_k<<<dim3(13, 13, 8), dim3(32, 8), 0, stream>>>(gcnW, Wt);

  // 1. qk = x @ Wk + bk  (split-bf16 MFMA: fp32-class accuracy at MFMA rate)
  xsplit_k<<<2600, 256, 0, stream>>>(x, xh, xl);
  wksplit_k<<<dim3(13, 16), dim3(32, 8), 0, stream>>>(Wk, 400, 512, 416, Wth, Wtl);
  sgemm_mfma<13, false, false><<<dim3(8, 100), 256, 0, stream>>>(
      xh, xl, Wth, Wtl, bk, qk, nullptr, nullptr, 512);

  // 2. SE gate
  gate_k<<<1, 64, 0, stream>>>(seW1, seb1, seW2, seb2, gate);

  // 3a. batched symmetric QK^T -> relu -> scores [51200,400]
  qkscore_k<<<dim3(7, 7, 128), 256, 0, stream>>>(qk, scores);

  // 3b. softmax+gate+rank -> 7-sparse adjacency (one wave per row)
  rankadj_k<<<12800, 256, 0, stream>>>(scores, gate, adjval, adjcol);

  // 4. 8x GCN: staged 32-col spmsg + counted-vmcnt bf16 MFMA GEMM
  for (int i = 0; i < 8; ++i) {
    const int first = (i == 0) ? 1 : 0;
    spmsg_k<<<dim3(BH, 13), 256, 0, stream>>>(adjcol, adjval, featsb, x,
                                              first, msg);
    gcn_gemm<<<dim3(2800), 256, 0, stream>>>(
        msg, Wt + (size_t)i * KP * KP, gcnb + (size_t)i * nT, featsb, x, first);
  }

  // 5+6a. fused head-fusion + split (reads featsb, writes mxh/mxl in msg region)
  hfx_k<<<2600, 256, 0, stream>>>(featsb, fw, fb, mxh, mxl);

  // 6b. MLP1 via split-bf16 MFMA, split-bf16 output (feeds MLP2 directly)
  wksplit_k<<<dim3(13, 8), dim3(32, 8), 0, stream>>>(mW1, 400, 256, 416, mWth, mWtl);
  sgemm_mfma<13, true, true><<<dim3(4, 100), 256, 0, stream>>>(
      mxh, mxl, mWth, mWtl, mb1, nullptr, h1h, h1l, 256);

  // 7. MLP2 via split-bf16 MFMA (K=256), split output
  wksplit_k<<<dim3(8, 4), dim3(32, 8), 0, stream>>>(mW2, 256, 128, 256, w2h, w2l);
  sgemm_mfma<8, true, true><<<dim3(2, 100), 256, 0, stream>>>(
      h1h, h1l, w2h, w2l, mb2, nullptr, h2h, h2l, 128);

  // 8. MLP3 via split-bf16 MFMA (K=128), fp32 output for tiny MLP4
  wksplit_k<<<dim3(4, 2), dim3(32, 8), 0, stream>>>(mW3, 128, 64, 128, w3h, w3l);
  sgemm_mfma<4, true, false><<<dim3(1, 100), 256, 0, stream>>>(
      h2h, h2l, w3h, w3l, mb3, h3, nullptr, nullptr, 64);

  // 9. MLP4 (fp32, N=5)
  gemm_k<64, 64, 16, 4, 4, true><<<dim3(1, 100), 256, 0, stream>>>(
      h3, mW4, mb4, out, 6400, 5, 64);
}

// Round 13
// 785.435 us; speedup vs baseline: 1.0494x; 1.0494x over previous
//
#include <hip/hip_runtime.h>
#include <math.h>

namespace {

constexpr int nB = 16, nR = 400, nT = 400, nH = 8, nQ = 64;
constexpr int BH = nB * nH;   // 128
constexpr int HQ = nH * nQ;   // 512
constexpr int KP = 416;       // padded K for bf16 GEMMs (13 x 32)
constexpr int NK = KP / 32;   // 13 K-chunks

typedef __attribute__((ext_vector_type(8))) short short8;
typedef __attribute__((ext_vector_type(4))) float floatx4;

__device__ __forceinline__ unsigned short f2bf(float f) {
  unsigned int u = __float_as_uint(f);
  unsigned int r = (u + 0x7fffu + ((u >> 16) & 1u)) >> 16;
  return (unsigned short)r;
}
__device__ __forceinline__ float bf2f(unsigned short u) {
  return __uint_as_float(((unsigned int)u) << 16);
}

// async global->LDS DMA, 16B per lane; LDS dest is wave-uniform base + lane*16
__device__ __forceinline__ void dma16(const void* g, void* l) {
  __builtin_amdgcn_global_load_lds(
      (const __attribute__((address_space(1))) unsigned int*)g,
      (__attribute__((address_space(3))) unsigned int*)l, 16, 0, 0);
}

// ---------------- generic fp32 GEMM: C = act(A@W + bias) ----------------
template<int BM, int BN, int BK, int TM, int TN, bool RELU>
__global__ __launch_bounds__(256) void gemm_k(
    const float* __restrict__ A, const float* __restrict__ W,
    const float* __restrict__ bias,
    float* C, int M, int N, int K)
{
  constexpr int NT = (BM / TM) * (BN / TN);
  static_assert(NT == 256, "block must be 256 threads");
  __shared__ float As[BK][BM + 4];
  __shared__ float Bs[BK][BN + 4];
  const int tid = threadIdx.x;
  const int bm = blockIdx.y * BM;
  const int bn = blockIdx.x * BN;
  const int tx = tid % (BN / TN);
  const int ty = tid / (BN / TN);
  const bool n4ok = ((N & 3) == 0);

  float acc[TM][TN];
#pragma unroll
  for (int i = 0; i < TM; ++i)
#pragma unroll
    for (int j = 0; j < TN; ++j) acc[i][j] = 0.f;

  for (int kt = 0; kt < K; kt += BK) {
#pragma unroll
    for (int i = 0; i < (BM * BK) / (NT * 4); ++i) {
      int flat = (tid + i * NT) * 4;
      int m = flat / BK;
      int k = flat % BK;
      float4 v = *(const float4*)(A + (size_t)(bm + m) * K + kt + k);
      As[k + 0][m] = v.x; As[k + 1][m] = v.y;
      As[k + 2][m] = v.z; As[k + 3][m] = v.w;
    }
#pragma unroll
    for (int i = 0; i < (BK * BN) / (NT * 4); ++i) {
      int flat = (tid + i * NT) * 4;
      int k = flat / BN;
      int n = flat % BN;
      int gn = bn + n;
      float4 v;
      if (n4ok && gn + 3 < N) {
        v = *(const float4*)(W + (size_t)(kt + k) * N + gn);
      } else {
        v.x = (gn + 0 < N) ? W[(size_t)(kt + k) * N + gn + 0] : 0.f;
        v.y = (gn + 1 < N) ? W[(size_t)(kt + k) * N + gn + 1] : 0.f;
        v.z = (gn + 2 < N) ? W[(size_t)(kt + k) * N + gn + 2] : 0.f;
        v.w = (gn + 3 < N) ? W[(size_t)(kt + k) * N + gn + 3] : 0.f;
      }
      *(float4*)&Bs[k][n] = v;
    }
    __syncthreads();
#pragma unroll
    for (int k = 0; k < BK; ++k) {
      float a[TM], b[TN];
#pragma unroll
      for (int i = 0; i < TM; i += 4)
        *(float4*)&a[i] = *(const float4*)&As[k][ty * TM + i];
#pragma unroll
      for (int j = 0; j < TN; j += 4)
        *(float4*)&b[j] = *(const float4*)&Bs[k][tx * TN + j];
#pragma unroll
      for (int i = 0; i < TM; ++i)
#pragma unroll
        for (int j = 0; j < TN; ++j) acc[i][j] += a[i] * b[j];
    }
    __syncthreads();
  }

#pragma unroll
  for (int i = 0; i < TM; ++i) {
    const int gm = bm + ty * TM + i;
    float* crow = C + (size_t)gm * N;
#pragma unroll
    for (int j = 0; j < TN; j += 4) {
      const int gn = bn + tx * TN + j;
      if (n4ok && gn + 3 < N) {
        float4 bv = *(const float4*)(bias + gn);
        float4 v;
        v.x = acc[i][j + 0] + bv.x; v.y = acc[i][j + 1] + bv.y;
        v.z = acc[i][j + 2] + bv.z; v.w = acc[i][j + 3] + bv.w;
        if (RELU) {
          v.x = fmaxf(v.x, 0.f); v.y = fmaxf(v.y, 0.f);
          v.z = fmaxf(v.z, 0.f); v.w = fmaxf(v.w, 0.f);
        }
        *(float4*)(crow + gn) = v;
      } else {
#pragma unroll
        for (int jj = 0; jj < 4; ++jj) {
          int gnn = gn + jj;
          if (gnn < N) {
            float v = acc[i][j + jj] + bias[gnn];
            if (RELU) v = fmaxf(v, 0.f);
            crow[gnn] = v;
          }
        }
      }
    }
  }
}

// ---------------- split-bf16 prep: rows [6400][400] fp32 -> hi/lo bf16 [6400][416]
__global__ void xsplit_k(const float* __restrict__ x,
                         unsigned short* __restrict__ xh,
                         unsigned short* __restrict__ xl)
{
  int i = blockIdx.x * 256 + threadIdx.x;      // 4-col group id
  constexpr int total = 6400 * (KP / 4);       // 665,600
  if (i >= total) return;
  int row = i / (KP / 4), cg = i - row * (KP / 4);
  int c = cg * 4;
  ushort4 h = make_ushort4(0, 0, 0, 0), l = make_ushort4(0, 0, 0, 0);
  if (c < 400) {
    float4 v = *(const float4*)(x + (size_t)row * 400 + c);
    h.x = f2bf(v.x); l.x = f2bf(v.x - bf2f(h.x));
    h.y = f2bf(v.y); l.y = f2bf(v.y - bf2f(h.y));
    h.z = f2bf(v.z); l.z = f2bf(v.z - bf2f(h.z));
    h.w = f2bf(v.w); l.w = f2bf(v.w - bf2f(h.w));
  }
  *(ushort4*)(xh + (size_t)row * KP + c) = h;
  *(ushort4*)(xl + (size_t)row * KP + c) = l;
}

// ---------------- fused head-fusion + split: feats(bf16,8 heads) -> xh/xl ------
// Replaces hfuse_k + the MLP1 xsplit pass: fused fp32 is never materialized.
__global__ void hfx_k(const unsigned short* __restrict__ feats,
                      const float* __restrict__ fw, const float* __restrict__ fb,
                      unsigned short* __restrict__ xh,
                      unsigned short* __restrict__ xl)
{
  int i = blockIdx.x * 256 + threadIdx.x;      // 4-col group id
  constexpr int total = 6400 * (KP / 4);       // 665,600
  if (i >= total) return;
  int row = i / (KP / 4), cg = i - row * (KP / 4);
  int c = cg * 4;
  ushort4 h = make_ushort4(0, 0, 0, 0), l = make_ushort4(0, 0, 0, 0);
  if (c < 400) {
    const int bb = row / nR;
    const int r = row - bb * nR;
    float fbv = fb[0];
    float4 acc = {fbv, fbv, fbv, fbv};
#pragma unroll
    for (int hh = 0; hh < nH; ++hh) {
      float w = fw[hh];
      ushort4 v = *(const ushort4*)(feats +
          (((size_t)(bb * nH + hh) * nR + r) * nT + c));
      acc.x += w * bf2f(v.x); acc.y += w * bf2f(v.y);
      acc.z += w * bf2f(v.z); acc.w += w * bf2f(v.w);
    }
    h.x = f2bf(acc.x); l.x = f2bf(acc.x - bf2f(h.x));
    h.y = f2bf(acc.y); l.y = f2bf(acc.y - bf2f(h.y));
    h.z = f2bf(acc.z); l.z = f2bf(acc.z - bf2f(h.z));
    h.w = f2bf(acc.w); l.w = f2bf(acc.w - bf2f(h.w));
  }
  *(ushort4*)(xh + (size_t)row * KP + c) = h;
  *(ushort4*)(xl + (size_t)row * KP + c) = l;
}

// ---------------- W prep: [400][N] fp32 -> n-major hi/lo bf16 [N][416] ---------
__global__ void wksplit_k(const float* __restrict__ W, int N,
                          unsigned short* __restrict__ Wth,
                          unsigned short* __restrict__ Wtl)
{
  __shared__ float t[32][33];
  const int k0 = blockIdx.x * 32;   // 13 tiles cover 416 (reads only k<400)
  const int n0 = blockIdx.y * 32;
  const int tx = threadIdx.x, ty = threadIdx.y;   // 32 x 8
#pragma unroll
  for (int r = 0; r < 32; r += 8) {
    int k = k0 + ty + r, n = n0 + tx;
    t[ty + r][tx] = (k < 400) ? W[(size_t)k * N + n] : 0.f;
  }
  __syncthreads();
#pragma unroll
  for (int r = 0; r < 32; r += 8) {
    int n = n0 + ty + r, k = k0 + tx;
    float v = t[tx][ty + r];
    unsigned short h = f2bf(v);
    Wth[(size_t)n * KP + k] = h;
    Wtl[(size_t)n * KP + k] = f2bf(v - bf2f(h));
  }
}

// ---------------- split-bf16 MFMA GEMM: C = act(A@W + bias), fp32-class accuracy
// C ~= Ah@Bh + Ah@Bl + Al@Bh  (dropped Al@Bl ~ 2^-18 relative).
template<bool RELU>
__global__ __launch_bounds__(256) void sgemm_mfma(
    const unsigned short* __restrict__ Ah, const unsigned short* __restrict__ Al,
    const unsigned short* __restrict__ Bh, const unsigned short* __restrict__ Bl,
    const float* __restrict__ bias,
    float* __restrict__ C, int N)
{
  // 3 x 16KB stage buffers; epilogue Os (64x68 fp32 = 17.4KB) aliases
  __shared__ __align__(16) char smem[49152];

  const int tid = threadIdx.x;
  const int lane = tid & 63;
  const int wave = tid >> 6;

  const int bm = blockIdx.y * 64;
  const int bn = blockIdx.x * 64;

  const int wm = (wave & 1) * 32;
  const int wn = (wave >> 1) * 32;

  // wave w stages kind w entirely: 0 Ah, 1 Al, 2 Bh, 3 Bl (4 x 1KB groups)
  const unsigned short* kbase = (wave == 0) ? Ah : (wave == 1) ? Al
                              : (wave == 2) ? Bh : Bl;
  const int rbase0 = (wave < 2) ? bm : bn;
  const unsigned short* gsrc[4];
  int goff[4];
#pragma unroll
  for (int j = 0; j < 4; ++j) {
    const int row = rbase0 + j * 16 + (lane & 15);
    gsrc[j] = kbase + (size_t)row * KP + (lane >> 4) * 8;
    goff[j] = (wave * 4 + j) * 1024;
  }

  // prologue: chunk 0 -> buf0, chunk 1 -> buf1
#pragma unroll
  for (int j = 0; j < 4; ++j) dma16(gsrc[j], smem + goff[j]);
#pragma unroll
  for (int j = 0; j < 4; ++j) dma16(gsrc[j] + 32, smem + 16384 + goff[j]);

  floatx4 acc[2][2] = {};
  const int ao = (wm >> 4) * 1024;            // {0, 2048}
  const int bo = (wn >> 4) * 1024;
  const int lb = lane * 16;

#pragma unroll
  for (int k = 0; k < NK; ++k) {
    if (k == NK - 1)
      asm volatile("s_waitcnt vmcnt(0)" ::: "memory");
    else
      asm volatile("s_waitcnt vmcnt(4)" ::: "memory");
    __builtin_amdgcn_s_barrier();
    __builtin_amdgcn_sched_barrier(0);
    if (k + 2 < NK) {
      char* dst = smem + ((k + 2) % 3) * 16384;
#pragma unroll
      for (int j = 0; j < 4; ++j)
        dma16(gsrc[j] + (k + 2) * 32, dst + goff[j]);
    }
    const char* base = smem + (k % 3) * 16384;
    short8 ah[2], al[2], bh[2], bl[2];
#pragma unroll
    for (int mi = 0; mi < 2; ++mi) {
      ah[mi] = *(const short8*)(base + ao + mi * 1024 + lb);
      al[mi] = *(const short8*)(base + 4096 + ao + mi * 1024 + lb);
    }
#pragma unroll
    for (int ni = 0; ni < 2; ++ni) {
      bh[ni] = *(const short8*)(base + 8192 + bo + ni * 1024 + lb);
      bl[ni] = *(const short8*)(base + 12288 + bo + ni * 1024 + lb);
    }
#pragma unroll
    for (int mi = 0; mi < 2; ++mi)
#pragma unroll
      for (int ni = 0; ni < 2; ++ni) {
        acc[mi][ni] = __builtin_amdgcn_mfma_f32_16x16x32_bf16(
            ah[mi], bh[ni], acc[mi][ni], 0, 0, 0);
        acc[mi][ni] = __builtin_amdgcn_mfma_f32_16x16x32_bf16(
            ah[mi], bl[ni], acc[mi][ni], 0, 0, 0);
        acc[mi][ni] = __builtin_amdgcn_mfma_f32_16x16x32_bf16(
            al[mi], bh[ni], acc[mi][ni], 0, 0, 0);
      }
  }

  float* Os = (float*)smem;   // aliases staging buffers
  __syncthreads();            // all waves' last ds_reads done before overwrite
#pragma unroll
  for (int mi = 0; mi < 2; ++mi)
#pragma unroll
    for (int ni = 0; ni < 2; ++ni)
#pragma unroll
      for (int r = 0; r < 4; ++r) {
        const int lrow = wm + mi * 16 + (lane >> 4) * 4 + r;
        const int cl = wn + ni * 16 + (lane & 15);
        Os[lrow * 68 + cl] = acc[mi][ni][r];
      }
  __syncthreads();

#pragma unroll
  for (int ii = 0; ii < 4; ++ii) {
    const int f = tid + ii * 256;     // 1024 slots = 64 rows x 16 float4 groups
    const int row = f >> 4;
    const int c4 = (f & 15) << 2;
    float4 v = *(const float4*)&Os[row * 68 + c4];
    float4 bb = *(const float4*)(bias + bn + c4);
    v.x += bb.x; v.y += bb.y; v.z += bb.z; v.w += bb.w;
    if (RELU) {
      v.x = fmaxf(v.x, 0.f); v.y = fmaxf(v.y, 0.f);
      v.z = fmaxf(v.z, 0.f); v.w = fmaxf(v.w, 0.f);
    }
    *(float4*)(C + (size_t)(bm + row) * N + bn + c4) = v;
  }
}

// ---------------- bf16 MFMA GEMM for GCN layers — counted-vmcnt pipeline ------
// R23 form (proven 787): R17 K-loop frozen + single-pass epilogue. Do not
// retile (R18 regressed); do not DMA-stage spmsg (R21 regressed).
__global__ __launch_bounds__(256) void gcn_gemm(
    const unsigned short* __restrict__ A,    // msg [51200][416] bf16
    const unsigned short* __restrict__ Bt,   // Wt [416][416] bf16 n-major
    const float* __restrict__ bias,
    unsigned short* __restrict__ Cb,         // feats [51200][400] bf16
    const float* __restrict__ x, int first)
{
  // 3 stage buffers x (A 8KB | B 4KB) = 36864 B; epilogue Os (34816 B) aliases
  __shared__ __align__(16) char smem[36864];

  const int tid = threadIdx.x;
  const int lane = tid & 63;
  const int wave = tid >> 6;

  // XCD-local decode: 350 blocks per XCD; n-tiles of one m-tile consecutive.
  const int b = blockIdx.x;
  const int xcd = b & 7;
  const int s = b >> 3;          // 0..349
  const int loc = s / 7;         // 0..49
  const int nt = s - loc * 7;    // 0..6
  const int mt = loc * 8 + xcd;  // 0..399
  const int bm = mt * 128;
  const int bn = nt * 64;

  const int wm = (wave & 1) * 64;
  const int wn = (wave >> 1) * 32;

  // --- DMA setup: 12 x 1KB groups per K-chunk (8 A + 4 B), 3 per wave.
  const unsigned short* gsrc[3];
  int goff[3];                       // byte offset within one 12KB buffer
#pragma unroll
  for (int j = 0; j < 3; ++j) {
    const int g = wave * 3 + j;
    if (g < 8) {
      const int row = bm + g * 16 + (lane & 15);
      gsrc[j] = A + (size_t)row * KP + (lane >> 4) * 8;
      goff[j] = g * 1024;
    } else {
      int row = bn + (g - 8) * 16 + (lane & 15);
      if (row > 415) row = 415;
      gsrc[j] = Bt + (size_t)row * KP + (lane >> 4) * 8;
      goff[j] = 8192 + (g - 8) * 1024;
    }
  }

  // Residual preload (T14): oldest vmem ops; drained by iter-0's vmcnt wait.
  const int rcol = bn + ((tid & 15) << 2);
  ushort4 resv[2][4];
  if (!first && rcol < nT) {
#pragma unroll
    for (int rh = 0; rh < 2; ++rh)
#pragma unroll
      for (int ii = 0; ii < 4; ++ii) {
        const int gr = bm + rh * 64 + (tid >> 4) + ii * 16;
        resv[rh][ii] = *(const ushort4*)(Cb + (size_t)gr * nT + rcol);
      }
  }

  // prologue: stage chunk 0 -> buf0, chunk 1 -> buf1
#pragma unroll
  for (int j = 0; j < 3; ++j)
    dma16(gsrc[j], smem + goff[j]);
#pragma unroll
  for (int j = 0; j < 3; ++j)
    dma16(gsrc[j] + 32, smem + 12288 + goff[j]);

  floatx4 acc[4][2] = {};
  const int aoff = (wm >> 4) * 1024;          // {0, 4096}
  const int boff = 8192 + (wn >> 4) * 1024;   // {8192, 10240}
  const int lb = lane * 16;

#pragma unroll
  for (int k = 0; k < NK; ++k) {
    // wait this wave's chunk-k stages; count = # newer in-flight stage ops
    if (k == NK - 1)
      asm volatile("s_waitcnt vmcnt(0)" ::: "memory");
    else
      asm volatile("s_waitcnt vmcnt(3)" ::: "memory");
    __builtin_amdgcn_s_barrier();            // all waves' chunk-k resident
    __builtin_amdgcn_sched_barrier(0);       // no ds_read migration upward
    if (k + 2 < NK) {                        // stage chunk k+2 (buffer read at k-1)
      char* dst = smem + ((k + 2) % 3) * 12288;
#pragma unroll
      for (int j = 0; j < 3; ++j)
        dma16(gsrc[j] + (k + 2) * 32, dst + goff[j]);
    }
    const char* base = smem + (k % 3) * 12288;
    short8 av[4], bv[2];
#pragma unroll
    for (int mi = 0; mi < 4; ++mi)
      av[mi] = *(const short8*)(base + aoff + mi * 1024 + lb);
#pragma unroll
    for (int ni = 0; ni < 2; ++ni)
      bv[ni] = *(const short8*)(base + boff + ni * 1024 + lb);
#pragma unroll
    for (int mi = 0; mi < 4; ++mi)
#pragma unroll
      for (int ni = 0; ni < 2; ++ni)
        acc[mi][ni] = __builtin_amdgcn_mfma_f32_16x16x32_bf16(
            av[mi], bv[ni], acc[mi][ni], 0, 0, 0);
  }

  // bias per ni (C/D layout: col = lane&15, row = (lane>>4)*4 + reg)
  float bvv[2];
#pragma unroll
  for (int ni = 0; ni < 2; ++ni) {
    const int col = bn + wn + ni * 16 + (lane & 15);
    bvv[ni] = (col < nT) ? bias[col] : 0.f;
  }

  float* Os = (float*)smem;   // 128 x 68 fp32 = 34816 B, aliases staging bufs

  // single-pass epilogue: all 4 waves write relu(acc+bias) for their own
  // 64-row slab (disjoint wm) -> one barrier pair, one 2048-item store pass.
  __syncthreads();            // all waves done reading chunk-12's buffer
#pragma unroll
  for (int mi = 0; mi < 4; ++mi)
#pragma unroll
    for (int ni = 0; ni < 2; ++ni)
#pragma unroll
      for (int r = 0; r < 4; ++r) {
        const int lrow = wm + mi * 16 + (lane >> 4) * 4 + r;
        const int cl = wn + ni * 16 + (lane & 15);
        Os[lrow * 68 + cl] = fmaxf(acc[mi][ni][r] + bvv[ni], 0.f);
      }
  __syncthreads();

#pragma unroll
  for (int ii = 0; ii < 8; ++ii) {
    const int f = tid + ii * 256;     // 2048 slots = 128 rows x 16 col-groups
    const int row = f >> 4;           // = ii*16 + (tid>>4)
    const int c4 = (f & 15) << 2;
    const int col = bn + c4;
    if (col < nT) {
      const int gr = bm + row;
      float4 v = *(const float4*)&Os[row * 68 + c4];
      float r0, r1, r2, r3;
      if (first) {
        const int bh = gr / nR;
        const int rr = gr - bh * nR;
        const float* rrow = x + (size_t)(bh >> 3) * (nR * nT) + (size_t)rr * nT;
        float4 rv = *(const float4*)(rrow + col);
        r0 = rv.x; r1 = rv.y; r2 = rv.z; r3 = rv.w;
      } else {
        ushort4 rv = resv[ii >> 2][ii & 3];   // same gr/rcol mapping as load
        r0 = bf2f(rv.x); r1 = bf2f(rv.y); r2 = bf2f(rv.z); r3 = bf2f(rv.w);
      }
      ushort4 o;
      o.x = f2bf(v.x + r0); o.y = f2bf(v.y + r1);
      o.z = f2bf(v.z + r2); o.w = f2bf(v.w + r3);
      *(ushort4*)(Cb + (size_t)gr * nT + col) = o;
    }
  }
}

// ---------------- W prep: Wt[i][n][k] = bf16(gcn_W[i][k][n]), zero-padded ------
__global__ void wprep_k(const float* __restrict__ W, unsigned short* __restrict__ Wt)
{
  __shared__ float t[32][33];
  const int i = blockIdx.z;
  const int k0 = blockIdx.x * 32;
  const int n0 = blockIdx.y * 32;
  const int tx = threadIdx.x, ty = threadIdx.y;   // 32 x 8
#pragma unroll
  for (int r = 0; r < 32; r += 8) {
    int k = k0 + ty + r, n = n0 + tx;
    t[ty + r][tx] = (k < nT && n < nT) ? W[(size_t)i * nT * nT + (size_t)k * nT + n] : 0.f;
  }
  __syncthreads();
#pragma unroll
  for (int r = 0; r < 32; r += 8) {
    int n = n0 + ty + r, k = k0 + tx;
    Wt[(size_t)i * KP * KP + (size_t)n * KP + k] = f2bf(t[tx][ty + r]);
  }
}

// ---------------- SE gate (gap == 1/R identically) -----------------------------
__global__ void gate_k(const float* __restrict__ w1, const float* __restrict__ b1,
                       const float* __restrict__ w2, const float* __restrict__ b2,
                       float* gate)
{
  if (threadIdx.x == 0 && blockIdx.x == 0) {
    float h1[4];
    const float gap = 1.0f / 400.0f;
#pragma unroll
    for (int i = 0; i < 4; ++i) {
      float s = b1[i];
      for (int h = 0; h < 8; ++h) s += gap * w1[h * 4 + i];
      h1[i] = fmaxf(s, 0.f);
    }
#pragma unroll
    for (int h = 0; h < 8; ++h) {
      float s = b2[h];
      for (int i = 0; i < 4; ++i) s += h1[i] * w2[i * 8 + h];
      gate[h] = 1.f / (1.f + expf(-s));
    }
  }
}

// ---------------- batched QK^T scores: sc = relu((Q@K^T)/8), symmetric ---------
__global__ __launch_bounds__(256) void qkscore_k(
    const float* __restrict__ qk, float* __restrict__ sc)
{
  __shared__ float Qs[64][68];   // Qs[k][m]
  __shared__ float Ks[64][68];   // Ks[k][n]

  const int tm = blockIdx.y;
  const int tn = blockIdx.x;
  if (tm > tn) return;           // symmetry: skip lower triangle

  const int tid = threadIdx.x;
  const int bh = blockIdx.z;
  const int b = bh >> 3, h = bh & 7;
  const int bm = tm * 64;
  const int bn = tn * 64;
  const float* qkb = qk + (size_t)b * nR * HQ + h * nQ;

  {
    const int row = tid & 63;                 // = lane -> conflict-free LDS writes
#pragma unroll
    for (int p = 0; p < 4; ++p) {
      const int kc = (tid >> 6) + p * 4;
      int gr = bm + row; if (gr > 399) gr = 399;
      float4 v = *(const float4*)(qkb + (size_t)gr * HQ + (kc << 2));
      Qs[kc * 4 + 0][row] = v.x; Qs[kc * 4 + 1][row] = v.y;
      Qs[kc * 4 + 2][row] = v.z; Qs[kc * 4 + 3][row] = v.w;
      int gs2 = bn + row; if (gs2 > 399) gs2 = 399;
      float4 w = *(const float4*)(qkb + (size_t)gs2 * HQ + (kc << 2));
      Ks[kc * 4 + 0][row] = w.x; Ks[kc * 4 + 1][row] = w.y;
      Ks[kc * 4 + 2][row] = w.z; Ks[kc * 4 + 3][row] = w.w;
    }
  }
  __syncthreads();

  const int tx = tid & 15;
  const int ty = tid >> 4;
  float acc[4][4] = {};
#pragma unroll 8
  for (int k = 0; k < 64; ++k) {
    float4 a = *(const float4*)&Qs[k][ty * 4];
    float4 bv = *(const float4*)&Ks[k][tx * 4];
    acc[0][0] += a.x * bv.x; acc[0][1] += a.x * bv.y; acc[0][2] += a.x * bv.z; acc[0][3] += a.x * bv.w;
    acc[1][0] += a.y * bv.x; acc[1][1] += a.y * bv.y; acc[1][2] += a.y * bv.z; acc[1][3] += a.y * bv.w;
    acc[2][0] += a.z * bv.x; acc[2][1] += a.z * bv.y; acc[2][2] += a.z * bv.z; acc[2][3] += a.z * bv.w;
    acc[3][0] += a.w * bv.x; acc[3][1] += a.w * bv.y; acc[3][2] += a.w * bv.z; acc[3][3] += a.w * bv.w;
  }

  float* scb = sc + (size_t)bh * nR * 400;

  {
    const int gc = bn + tx * 4;
    if (gc < 400) {
#pragma unroll
      for (int i = 0; i < 4; ++i) {
        const int gr = bm + ty * 4 + i;
        if (gr < 400) {
          float4 o;
          o.x = fmaxf(acc[i][0] * 0.125f, 0.f);
          o.y = fmaxf(acc[i][1] * 0.125f, 0.f);
          o.z = fmaxf(acc[i][2] * 0.125f, 0.f);
          o.w = fmaxf(acc[i][3] * 0.125f, 0.f);
          *(float4*)(scb + (size_t)gr * 400 + gc) = o;
        }
      }
    }
  }

  if (tm != tn) {
    const int gc = bm + ty * 4;
    if (gc < 400) {
#pragma unroll
      for (int j = 0; j < 4; ++j) {
        const int gr = bn + tx * 4 + j;
        if (gr < 400) {
          float4 o;
          o.x = fmaxf(acc[0][j] * 0.125f, 0.f);
          o.y = fmaxf(acc[1][j] * 0.125f, 0.f);
          o.z = fmaxf(acc[2][j] * 0.125f, 0.f);
          o.w = fmaxf(acc[3][j] * 0.125f, 0.f);
          *(float4*)(scb + (size_t)gr * 400 + gc) = o;
        }
      }
    }
  }
}

// ---------------- softmax + gate + stable-rank mask -> sparse adj --------------
__global__ __launch_bounds__(256) void rankadj_k(
    const float* __restrict__ sc, const float* __restrict__ gate,
    float* __restrict__ adjval, int* __restrict__ adjcol)
{
  __shared__ float rowbuf[4][408];

  const int wave = threadIdx.x >> 6;
  const int lane = threadIdx.x & 63;
  const int row = blockIdx.x * 4 + wave;
  const int bh = row / nR;
  const int r = row - bh * nR;
  const float* srow = sc + (size_t)row * 400;

  float v[7];
  bool valid[7];
#pragma unroll
  for (int it = 0; it < 7; ++it) {
    const int j = lane + it * 64;
    valid[it] = (j < 400);
    v[it] = valid[it] ? srow[j] : 0.f;
  }

  float m = 0.f;
#pragma unroll
  for (int it = 0; it < 7; ++it) m = fmaxf(m, v[it]);
#pragma unroll
  for (int o = 32; o > 0; o >>= 1) m = fmaxf(m, __shfl_xor(m, o));

  float e[7];
  float s = 0.f;
#pragma unroll
  for (int it = 0; it < 7; ++it) {
    e[it] = valid[it] ? expf(v[it] - m) : 0.f;
    s += e[it];
  }
#pragma unroll
  for (int o = 32; o > 0; o >>= 1) s += __shfl_xor(s, o);

  const float g = gate[bh & 7];
  float val[7];
#pragma unroll
  for (int it = 0; it < 7; ++it) val[it] = (e[it] / s) * g;

#pragma unroll
  for (int it = 0; it < 7; ++it)
    if (valid[it]) rowbuf[wave][lane + it * 64] = val[it];
  __syncthreads();

  const int csp[6] = {0, 16, 17, 18, 19, 20};
  float vc[6];
#pragma unroll
  for (int i = 0; i < 6; ++i) vc[i] = rowbuf[wave][csp[i]];
  int rk[6] = {0, 0, 0, 0, 0, 0};
#pragma unroll
  for (int it = 0; it < 7; ++it) {
    if (valid[it]) {
      const int j = lane + it * 64;
      const float vj = val[it];
#pragma unroll
      for (int i = 0; i < 6; ++i)
        rk[i] += (vj < vc[i]) ? 1 : ((vj == vc[i] && j < csp[i]) ? 1 : 0);
    }
  }
#pragma unroll
  for (int i = 0; i < 6; ++i)
#pragma unroll
    for (int o = 32; o > 0; o >>= 1) rk[i] += __shfl_xor(rk[i], o);

  if (lane == 0) {
    const size_t base = (size_t)row * 8;
    bool dup = false;
#pragma unroll
    for (int i = 0; i < 6; ++i) {
      const int p = rk[i];
      adjcol[base + i] = p;
      adjval[base + i] = rowbuf[wave][p];
      dup = dup || (p == r);
    }
    adjcol[base + 6] = r;
    adjval[base + 6] = dup ? 0.f : rowbuf[wave][r];
    adjcol[base + 7] = r;
    adjval[base + 7] = 0.f;
  }
}

// ---------------- sparse msg via LDS-staged feats(bf16), 32-col chunks ---------
// R20's exact spmsg (proven). 72B stride (18 dwords, gcd(18,32)=2) spreads
// random gather rows over 16 bank positions; DMA staging cannot express this
// layout (R21 regressed); 32B/item gather regressed (R24). Frozen.
__global__ __launch_bounds__(256) void spmsg_k(
    const int* __restrict__ adjcol, const float* __restrict__ adjval,
    const unsigned short* __restrict__ feats, const float* __restrict__ x,
    int first, unsigned short* __restrict__ msg)
{
  __shared__ unsigned short fs[400 * 36];   // 28.8 KB

  const int tid = threadIdx.x;
  const int bh = blockIdx.x;
  const int c0 = blockIdx.y * 32;           // 13 chunks cover 416 (>=400 pad)

  // stage: 400 rows x 32 cols bf16, 16B per item (r, g: 8-col group)
  if (first) {
    const float* src = x + (size_t)(bh >> 3) * (nR * nT);
    for (int i = tid; i < 1600; i += 256) {
      const int r = i >> 2, g = i & 3;
      const int c = c0 + g * 8;
      ushort4 lo = make_ushort4(0, 0, 0, 0), hi = make_ushort4(0, 0, 0, 0);
      if (c < 400) {
        float4 v0 = *(const float4*)(src + (size_t)r * nT + c);
        float4 v1 = *(const float4*)(src + (size_t)r * nT + c + 4);
        lo = make_ushort4(f2bf(v0.x), f2bf(v0.y), f2bf(v0.z), f2bf(v0.w));
        hi = make_ushort4(f2bf(v1.x), f2bf(v1.y), f2bf(v1.z), f2bf(v1.w));
      }
      *(ushort4*)&fs[r * 36 + g * 8] = lo;
      *(ushort4*)&fs[r * 36 + g * 8 + 4] = hi;
    }
  } else {
    const unsigned short* src = feats + (size_t)bh * nR * nT;
    for (int i = tid; i < 1600; i += 256) {
      const int r = i >> 2, g = i & 3;
      const int c = c0 + g * 8;
      short8 v = {};
      if (c < 400) v = *(const short8*)(src + (size_t)r * nT + c);
      *(short8*)&fs[r * 36 + g * 8] = v;
    }
  }
  __syncthreads();

  const int* ac = adjcol + (size_t)bh * nR * 8;
  const float* av = adjval + (size_t)bh * nR * 8;
  for (int i = tid; i < 1600; i += 256) {
    const int r = i >> 2, g = i & 3;
    const int c = c0 + g * 8;
    unsigned short* o = msg + ((size_t)bh * nR + r) * KP + c;
    if (c >= 400) {               // pad cols 400-415: must be zero for GEMM
      short8 z = {};
      *(short8*)o = z;
      continue;
    }
    int4 c03 = *(const int4*)(ac + r * 8);
    int4 c47 = *(const int4*)(ac + r * 8 + 4);
    float4 v03 = *(const float4*)(av + r * 8);
    float4 v47 = *(const float4*)(av + r * 8 + 4);
    const int col[7] = {c03.x, c03.y, c03.z, c03.w, c47.x, c47.y, c47.z};
    const float val[7] = {v03.x, v03.y, v03.z, v03.w, v47.x, v47.y, v47.z};
    float a[8] = {};
#pragma unroll
    for (int j = 0; j < 7; ++j) {
      short8 v = *(const short8*)&fs[col[j] * 36 + g * 8];
      const float w = val[j];
#pragma unroll
      for (int e = 0; e < 8; ++e)
        a[e] += w * bf2f((unsigned short)v[e]);
    }
    short8 ov;
#pragma unroll
    for (int e = 0; e < 8; ++e) ov[e] = (short)f2bf(a[e]);
    *(short8*)o = ov;
  }
}

}  // namespace

extern "C" void kernel_launch(void* const* d_in, const int* in_sizes, int n_in,
                              void* d_out, int out_size, void* d_ws, size_t ws_size,
                              hipStream_t stream)
{
  (void)in_sizes; (void)n_in; (void)out_size; (void)ws_size;
  const float* x    = (const float*)d_in[0];
  const float* Wk   = (const float*)d_in[1];
  const float* bk   = (const float*)d_in[2];
  const float* seW1 = (const float*)d_in[3];
  const float* seb1 = (const float*)d_in[4];
  const float* seW2 = (const float*)d_in[5];
  const float* seb2 = (const float*)d_in[6];
  const float* gcnW = (const float*)d_in[7];
  const float* gcnb = (const float*)d_in[8];
  const float* fw   = (const float*)d_in[9];
  const float* fb   = (const float*)d_in[10];
  const float* mW1  = (const float*)d_in[11];
  const float* mb1  = (const float*)d_in[12];
  const float* mW2  = (const float*)d_in[13];
  const float* mb2  = (const float*)d_in[14];
  const float* mW3  = (const float*)d_in[15];
  const float* mb3  = (const float*)d_in[16];
  const float* mW4  = (const float*)d_in[17];
  const float* mb4  = (const float*)d_in[18];
  float* out = (float*)d_out;

  // workspace (float units), total ~103 MB:
  // [adjval][adjcol][gate][Wt][qk][region: scores fp32 (82MB) ∪
  //   {featsb bf16 41MB ; msg bf16 42.6MB}]
  float* ws     = (float*)d_ws;
  float* adjval = ws;                                         //   409,600 f
  int*   adjcol = (int*)(adjval + 409600);                    //   409,600 i
  float* gate   = (float*)(adjcol + 409600);                  //        64 f
  unsigned short* Wt = (unsigned short*)(gate + 64);          //   692,224 f
  float* qk     = gate + 64 + 692224;                         // 3,276,800 f
  float* region = qk + (size_t)3276800;
  float* scores = region;                                     // 20,480,000 f
  unsigned short* featsb = (unsigned short*)region;           // 10,240,000 f-eq
  unsigned short* msg = (unsigned short*)(region + 10240000); // 10,649,600 f-eq

  // qk-path split-bf16 operand aliases (scores region, dead before scores write)
  unsigned short* xh  = (unsigned short*)region;              // 6400*416
  unsigned short* xl  = xh + (size_t)6400 * KP;
  unsigned short* Wth = xl + (size_t)6400 * KP;               // 512*416
  unsigned short* Wtl = Wth + (size_t)512 * KP;

  // MLP-path aliases live in the MSG region (dead after last gcn_gemm).
  unsigned short* mxh  = (unsigned short*)msg;                // 6400*416
  unsigned short* mxl  = mxh + (size_t)6400 * KP;
  unsigned short* mWth = mxl + (size_t)6400 * KP;             // 256*416
  unsigned short* mWtl = mWth + (size_t)256 * KP;
  float* h1 = (float*)(mWtl + (size_t)256 * KP);              // 6400*256
  float* h2 = h1 + (size_t)6400 * 256;                        // 6400*128
  float* h3 = h2 + (size_t)6400 * 128;                        // 6400*64

  // 0. gcn_W -> bf16, transposed (n-major), zero-padded to 416x416
  wprep_k<<<dim3(13, 13, 8), dim3(32, 8), 0, stream>>>(gcnW, Wt);

  // 1. qk = x @ Wk + bk  (split-bf16 MFMA: fp32-class accuracy at MFMA rate)
  xsplit_k<<<2600, 256, 0, stream>>>(x, xh, xl);
  wksplit_k<<<dim3(13, 16), dim3(32, 8), 0, stream>>>(Wk, 512, Wth, Wtl);
  sgemm_mfma<false><<<dim3(8, 100), 256, 0, stream>>>(
      xh, xl, Wth, Wtl, bk, qk, 512);

  // 2. SE gate
  gate_k<<<1, 64, 0, stream>>>(seW1, seb1, seW2, seb2, gate);

  // 3a. batched symmetric QK^T -> relu -> scores [51200,400]
  qkscore_k<<<dim3(7, 7, 128), 256, 0, stream>>>(qk, scores);

  // 3b. softmax+gate+rank -> 7-sparse adjacency (one wave per row)
  rankadj_k<<<12800, 256, 0, stream>>>(scores, gate, adjval, adjcol);

  // 4. 8x GCN: staged 32-col spmsg (R20) + counted-vmcnt bf16 MFMA GEMM
  for (int i = 0; i < 8; ++i) {
    const int first = (i == 0) ? 1 : 0;
    spmsg_k<<<dim3(BH, 13), 256, 0, stream>>>(adjcol, adjval, featsb, x,
                                              first, msg);
    gcn_gemm<<<dim3(2800), 256, 0, stream>>>(
        msg, Wt + (size_t)i * KP * KP, gcnb + (size_t)i * nT, featsb, x, first);
  }

  // 5+6a. fused head-fusion + split (reads featsb, writes mxh/mxl in msg region)
  hfx_k<<<2600, 256, 0, stream>>>(featsb, fw, fb, mxh, mxl);

  // 6b. MLP1 via split-bf16 MFMA
  wksplit_k<<<dim3(13, 8), dim3(32, 8), 0, stream>>>(mW1, 256, mWth, mWtl);
  sgemm_mfma<true><<<dim3(4, 100), 256, 0, stream>>>(
      mxh, mxl, mWth, mWtl, mb1, h1, 256);

  // 7-9. rest of MLP head (fp32)
  gemm_k<64, 64, 16, 4, 4, true><<<dim3(2, 100), 256, 0, stream>>>(
      h1, mW2, mb2, h2, 6400, 128, 256);
  gemm_k<64, 64, 16, 4, 4, true><<<dim3(1, 100), 256, 0, stream>>>(
      h2, mW3, mb3, h3, 6400, 64, 128);
  gemm_k<64, 64, 16, 4, 4, true><<<dim3(1, 100), 256, 0, stream>>>(
      h3, mW4, mb4, out, 6400, 5, 64);
}